// Round 4
// baseline (195.409 us; speedup 1.0000x reference)
//
#include <hip/hip_runtime.h>
#include <math.h>

#define NSTEPS 216
#define RPB 4            // rows (waves) per block
#define BLK 256

// Per-step table: {th, H*z0_t, K^-s, K^s}. Rebuilt every call (graph-safe).
__device__ float4 g_tbl[NSTEPS];

__global__ void traj_kernel() {
    __shared__ float xs[NSTEPS], ys[NSTEPS], kps[NSTEPS], kis[NSTEPS];
    const int t = threadIdx.x;
    if (t == 0) {
        // Serial part: x/y recurrence (R3's exact float ops — validated),
        // plus f64 K-power products (independent chain, overlaps).
        float x = (float)(-0.417750770388669);
        float y = (float)(-0.9085616622823985);
        const float W = (float)(2.0 * M_PI);
        const float H = 1.0f / 216.0f;
        const double Kd = (double)(1.0f - H);
        const double Kid = 1.0 / Kd;
        double kp = 1.0, ki = 1.0;
        for (int n = 0; n < NSTEPS; ++n) {
            xs[n] = x;  ys[n] = y;
            kps[n] = (float)kp;  kis[n] = (float)ki;
            float alpha = 1.0f - sqrtf(x * x + y * y);
            float fx = alpha * x - W * y;
            float fy = alpha * y + W * x;
            x = x + H * fx;
            y = y + H * fy;
            kp *= Kd;  ki *= Kid;
        }
    }
    __syncthreads();
    if (t < NSTEPS) {
        float th = atan2f(ys[t], xs[t]);                 // parallel atan2
        float tf = (float)t / 216.0f;
        float hz0 = (1.0f / 216.0f) * (0.005f * sinf(1.5707964f * tf));
        g_tbl[t] = make_float4(th, hz0, kis[t], kps[t]);
    }
}

// One wave per row. Lanes 0..53 own 4 consecutive time-slots each (54*4=216);
// lanes 54..63 duplicate the tail slots (harmless: their scan position is after
// all real lanes, and they are excluded from min/max and stores).
__global__ __launch_bounds__(BLK) void euler_kernel(const float* __restrict__ prm,
                                                    const float* __restrict__ v0,
                                                    float* __restrict__ out) {
    const int lane = threadIdx.x & 63;
    const int wav  = threadIdx.x >> 6;
    const int row  = blockIdx.x * RPB + wav;

    const float* p = prm + (size_t)row * 15;
    float tj[5], cj[5], la[5];
#pragma unroll
    for (int j = 0; j < 5; ++j) {
        float a  = p[3 * j + 0];
        float bb = p[3 * j + 1];
        tj[j] = p[3 * j + 2];
        cj[j] = -1.0f / (2.0f * bb * bb);
        la[j] = __logf(a);      // a*d*exp(q) = d*exp(q + ln a)
    }
    const float z0v = v0[row];
    const float H = 1.0f / 216.0f;
    const float K = 1.0f - H;

    int sb = lane * 4;
    if (sb > NSTEPS - 4) sb = NSTEPS - 4;   // pad lanes duplicate tail

    float loc[4], zK[4];
    float run = 0.0f;
#pragma unroll
    for (int q = 0; q < 4; ++q) {
        float4 e = g_tbl[sb + q];
        float th = e.x;
        float G = 0.0f;
#pragma unroll
        for (int j = 0; j < 5; ++j) {
            float d = th - tj[j];
            G = fmaf(d, __expf(fmaf(d * d, cj[j], la[j])), G);
        }
        float u = fmaf(-H, G, e.y);        // H*z0_t - H*G
        run += e.z * u;                    // w_s = K^-s * u_s
        loc[q] = run;                      // local inclusive prefix
        zK[q] = e.w;                       // K^s
    }

    // wave-inclusive scan of per-lane totals
    float scan = run;
#pragma unroll
    for (int d = 1; d < 64; d <<= 1) {
        float o = __shfl_up(scan, (unsigned)d, 64);
        if (lane >= d) scan += o;
    }
    const float excl = scan - run;

    // z_{s+1} = K^s * (K*z0 + P_incl(s))
    const float Kz0 = K * z0v;
    float z[4];
    float zmin = 3.4e38f, zmax = -3.4e38f;
#pragma unroll
    for (int q = 0; q < 4; ++q) {
        z[q] = zK[q] * (Kz0 + (excl + loc[q]));
        zmin = fminf(zmin, z[q]);
        zmax = fmaxf(zmax, z[q]);
    }
    if (lane >= 54) { zmin = 3.4e38f; zmax = -3.4e38f; }  // pad z is wrong; exclude
#pragma unroll
    for (int d = 1; d < 64; d <<= 1) {
        zmin = fminf(zmin, __shfl_xor(zmin, d, 64));
        zmax = fmaxf(zmax, __shfl_xor(zmax, d, 64));
    }
    const float s = 0.042557f / (zmax - zmin);
    const float o = fmaf(-zmin, s, -0.01563f);

    if (lane < 54) {
        float4 v = { fmaf(z[0], s, o), fmaf(z[1], s, o),
                     fmaf(z[2], s, o), fmaf(z[3], s, o) };
        *(float4*)(out + (size_t)row * NSTEPS + lane * 4) = v;
    }
}

extern "C" void kernel_launch(void* const* d_in, const int* in_sizes, int n_in,
                              void* d_out, int out_size, void* d_ws, size_t ws_size,
                              hipStream_t stream) {
    const float* x  = (const float*)d_in[0];
    const float* v0 = (const float*)d_in[1];
    float* out = (float*)d_out;
    const int nb = in_sizes[1];              // 131072 rows

    hipLaunchKernelGGL(traj_kernel, dim3(1), dim3(256), 0, stream);
    hipLaunchKernelGGL(euler_kernel, dim3(nb / RPB), dim3(BLK), 0, stream, x, v0, out);
}